// Round 1
// baseline (293.719 us; speedup 1.0000x reference)
//
#include <hip/hip_runtime.h>

#define B_    16
#define CIN   32
#define H_    128
#define W_    128
#define COUT  32
#define OH_   256
#define OW_   256

// Tile: 8x8 "cells" (a cell = 2x2 output pixels) = 16x16 outputs per block,
// for all 32 output channels. Block = 256 threads: co = tid>>3, sid = tid&7.
__global__ __launch_bounds__(256)
void convt_direct_kernel(const float* __restrict__ x,
                         const float* __restrict__ wgt,
                         const float* __restrict__ bias,
                         float* __restrict__ y) {
    // input patch: ih in [t0-1, t0+8] (10 rows), iw in [u0-1, u0+8] (10 cols),
    // padded to 12 cols so rows are 48B-aligned for ds_read_b128.
    __shared__ float xs[CIN][10][12];

    const int tid = threadIdx.x;
    const int n  = blockIdx.z;
    const int t0 = blockIdx.y * 8;   // cell-row base  (output row base = 2*t0)
    const int u0 = blockIdx.x * 8;   // cell-col base

    // ---- stage input patch (zero-padded at borders) ----
    for (int idx = tid; idx < CIN * 10 * 12; idx += 256) {
        int ci  = idx / 120;
        int rem = idx - ci * 120;
        int r   = rem / 12;
        int c   = rem - r * 12;
        int ih  = t0 - 1 + r;
        int iw  = u0 - 1 + c;
        float v = 0.0f;
        if (c < 10 && (unsigned)ih < H_ && (unsigned)iw < W_)
            v = x[((n * CIN + ci) * H_ + ih) * W_ + iw];
        xs[ci][r][c] = v;
    }
    __syncthreads();

    const int co  = tid >> 3;
    const int sid = tid & 7;

    float acc[2][16];
    const float bv = bias[co];
#pragma unroll
    for (int q = 0; q < 16; ++q) { acc[0][q] = bv; acc[1][q] = bv; }

    const float* wbase = wgt + co * 16;   // + ci * COUT*16

    for (int ci = 0; ci < CIN; ++ci) {
        const float4* wp = (const float4*)(wbase + ci * (COUT * 16));
        float4 w0 = wp[0];   // kh=0: (kw0,kw1,kw2,kw3) = (x,y,z,w)
        float4 w1 = wp[1];
        float4 w2 = wp[2];
        float4 w3 = wp[3];

        // rows: r0 = ih=t-1 (lds row sid), r1 = ih=t (sid+1), r2 = ih=t+1 (sid+2)
        float r0[12], r1[12], r2[12];
#pragma unroll
        for (int v = 0; v < 3; ++v) {
            ((float4*)r0)[v] = *(const float4*)&xs[ci][sid + 0][4 * v];
            ((float4*)r1)[v] = *(const float4*)&xs[ci][sid + 1][4 * v];
            ((float4*)r2)[v] = *(const float4*)&xs[ci][sid + 2][4 * v];
        }

#pragma unroll
        for (int j = 0; j < 8; ++j) {
            // oh even (po=0): x[t]*w[kh=1] + x[t-1]*w[kh=3]
            // ow even (qo=0): iw=u -> kw=1 (col j+1), iw=u-1 -> kw=3 (col j)
            acc[0][2 * j + 0] += w1.y * r1[j + 1] + w1.w * r1[j]
                               + w3.y * r0[j + 1] + w3.w * r0[j];
            // ow odd (qo=1): iw=u+1 -> kw=0 (col j+2), iw=u -> kw=2 (col j+1)
            acc[0][2 * j + 1] += w1.x * r1[j + 2] + w1.z * r1[j + 1]
                               + w3.x * r0[j + 2] + w3.z * r0[j + 1];
            // oh odd (po=1): x[t+1]*w[kh=0] + x[t]*w[kh=2]
            acc[1][2 * j + 0] += w0.y * r2[j + 1] + w0.w * r2[j]
                               + w2.y * r1[j + 1] + w2.w * r1[j];
            acc[1][2 * j + 1] += w0.x * r2[j + 2] + w0.z * r2[j + 1]
                               + w2.x * r1[j + 2] + w2.z * r1[j + 1];
        }
    }

    // ---- store: oh = 2*(t0+sid)+po, ow = 2*u0 .. 2*u0+15 (64B-aligned lines)
#pragma unroll
    for (int po = 0; po < 2; ++po) {
        int oh = 2 * (t0 + sid) + po;
        float* yp = y + (((long)n * COUT + co) * OH_ + oh) * OW_ + 2 * u0;
#pragma unroll
        for (int v = 0; v < 4; ++v)
            ((float4*)yp)[v] = make_float4(acc[po][4 * v + 0], acc[po][4 * v + 1],
                                           acc[po][4 * v + 2], acc[po][4 * v + 3]);
    }
}

extern "C" void kernel_launch(void* const* d_in, const int* in_sizes, int n_in,
                              void* d_out, int out_size, void* d_ws, size_t ws_size,
                              hipStream_t stream) {
    const float* x = (const float*)d_in[0];
    const float* w = (const float*)d_in[1];
    const float* b = (const float*)d_in[2];
    float* y = (float*)d_out;

    dim3 grid(OW_ / 16, OH_ / 16, B_);   // 16 x 16 x 16
    convt_direct_kernel<<<grid, 256, 0, stream>>>(x, w, b, y);
}

// Round 2
// 181.011 us; speedup vs baseline: 1.6227x; 1.6227x over previous
//
#include <hip/hip_runtime.h>

#define B_    16
#define CIN   32
#define H_    128
#define W_    128
#define COUT  32
#define OH_   256
#define OW_   256
#define HP    130   // padded h (1 halo each side)
#define WP    130   // padded w

typedef __attribute__((ext_vector_type(8))) short bf8_t;   // 8 bf16 (4 VGPRs)
typedef __attribute__((ext_vector_type(4))) float f32x4;

__device__ inline unsigned short f2bf(float f) {
    unsigned int u = __float_as_uint(f);
    unsigned int r = (u + 0x7fffu + ((u >> 16) & 1u)) >> 16;   // RNE
    return (unsigned short)r;
}

// ---- pre-kernel: weights f32 [ci][co][kh][kw] -> bf16 wt[kh*4+kw][co][ci] ----
__global__ __launch_bounds__(256)
void prep_w(const float* __restrict__ wgt, unsigned short* __restrict__ wt) {
    for (int e = threadIdx.x; e < 16 * 32 * 32; e += 256) {
        int khkw = e >> 10;
        int co   = (e >> 5) & 31;
        int ci   = e & 31;
        wt[e] = f2bf(wgt[(ci * COUT + co) * 16 + khkw]);
    }
}

// ---- pre-kernel: x f32 [n][ci][h][w] -> bf16 xt[n][hp][wp][32ci], swizzled ----
// ci-group g (8 ci) stored at chunk slot (g ^ ((w>>1)&3)) within each 64B cell.
__global__ __launch_bounds__(256)
void prep_x(const float* __restrict__ x, unsigned short* __restrict__ xt) {
    const int n = blockIdx.y;
    const int h = blockIdx.x * 2 + (threadIdx.x >> 7);
    const int w = threadIdx.x & 127;
    const float* xp = x + (((long)n * CIN) * H_ + h) * W_ + w;
    unsigned short* op = xt + (((long)n * HP + (h + 1)) * WP + (w + 1)) * 32;
    const int sw = (w >> 1) & 3;
#pragma unroll
    for (int g = 0; g < 4; ++g) {
        union { unsigned short s[8]; uint4 q; } pk;
#pragma unroll
        for (int j = 0; j < 8; ++j)
            pk.s[j] = f2bf(xp[(long)(g * 8 + j) * (H_ * W_)]);
        *(uint4*)(op + (g ^ sw) * 8) = pk.q;
    }
}

// ---- main kernel: per block: 2 t-rows x 64 u-cols, all 32 co, 4 parities ----
// wave = (trow = wv>>1, cohalf = wv&1). MFMA: A = w (M=co), B = x (N=pixels).
__global__ __launch_bounds__(256)
void convt_mfma(const unsigned short* __restrict__ xt,
                const unsigned short* __restrict__ wt,
                const float* __restrict__ bias,
                float* __restrict__ y) {
    __shared__ unsigned short xs[4 * 66 * 32];   // 16896 B

    const int tid  = threadIdx.x;
    const int lane = tid & 63;
    const int wv   = tid >> 6;
    const int n    = blockIdx.z;
    const int t0   = blockIdx.y * 2;
    const int u0   = blockIdx.x * 64;

    // stage 4 padded rows (h = t0-1 .. t0+2), w = u0-1 .. u0+64 (66 cells, 4224B/row)
    {
        const int r = wv;
        const unsigned short* gsrc = xt + (((long)n * HP + (t0 + r)) * WP + u0) * 32;
        unsigned short* lrow = xs + r * (66 * 32);
#pragma unroll
        for (int it = 0; it < 5; ++it) {
            int c = it * 64 + lane;
            if (c < 264) {
                __builtin_amdgcn_global_load_lds(
                    (const __attribute__((address_space(1))) void*)(gsrc + c * 8),
                    (__attribute__((address_space(3))) void*)(lrow + c * 8),
                    16, 0, 0);
            }
        }
    }

    const int ch   = wv & 1;      // co half
    const int trow = wv >> 1;     // 0..1
    const int g    = lane >> 4;   // k-chunk (ci group)
    const int li   = lane & 15;   // A: co row / B: pixel col

    // weight A-frags: 16 (kh,kw), this wave's co-half (registers, L2-hot reads)
    bf8_t wf[16];
    {
        const unsigned short* wp = wt + (ch * 16 + li) * 32 + g * 8;
#pragma unroll
        for (int kk = 0; kk < 16; ++kk)
            wf[kk] = *(const bf8_t*)(wp + kk * 1024);
    }
    float bias4[4];
#pragma unroll
    for (int r = 0; r < 4; ++r) bias4[r] = bias[ch * 16 + g * 4 + r];

    __syncthreads();   // drains global_load_lds (vmcnt) + barrier

    const int t = t0 + trow;
#pragma unroll
    for (int st = 0; st < 4; ++st) {
        const int us = u0 + st * 16;   // global u of pixel 0

        // x B-frags: xf[dh][dw] for Δh,Δw in {-1,0,1}
        bf8_t xf[3][3];
#pragma unroll
        for (int dh = 0; dh < 3; ++dh) {
#pragma unroll
            for (int dw = 0; dw < 3; ++dw) {
                int wg   = us + li + dw - 1;          // global w
                int wl   = wg - (u0 - 1);             // 0..65
                int slot = g ^ ((wg >> 1) & 3);
                int hl   = trow + dh;                 // 0..3
                xf[dh][dw] = *(const bf8_t*)(xs + (hl * 66 + wl) * 32 + slot * 8);
            }
        }

        f32x4 acc[2][2];
#pragma unroll
        for (int po = 0; po < 2; ++po)
#pragma unroll
            for (int qo = 0; qo < 2; ++qo)
                acc[po][qo] = (f32x4){bias4[0], bias4[1], bias4[2], bias4[3]};

#pragma unroll
        for (int po = 0; po < 2; ++po) {
            const int dh0 = po ? 2 : 1, kh0 = po ? 0 : 1;   // tap A: (Δh, kh)
            const int dh1 = po ? 1 : 0, kh1 = po ? 2 : 3;   // tap B
#pragma unroll
            for (int qo = 0; qo < 2; ++qo) {
                const int dw0 = qo ? 2 : 1, kw0 = qo ? 0 : 1;
                const int dw1 = qo ? 1 : 0, kw1 = qo ? 2 : 3;
                acc[po][qo] = __builtin_amdgcn_mfma_f32_16x16x32_bf16(
                    wf[kh0 * 4 + kw0], xf[dh0][dw0], acc[po][qo], 0, 0, 0);
                acc[po][qo] = __builtin_amdgcn_mfma_f32_16x16x32_bf16(
                    wf[kh0 * 4 + kw1], xf[dh0][dw1], acc[po][qo], 0, 0, 0);
                acc[po][qo] = __builtin_amdgcn_mfma_f32_16x16x32_bf16(
                    wf[kh1 * 4 + kw0], xf[dh1][dw0], acc[po][qo], 0, 0, 0);
                acc[po][qo] = __builtin_amdgcn_mfma_f32_16x16x32_bf16(
                    wf[kh1 * 4 + kw1], xf[dh1][dw1], acc[po][qo], 0, 0, 0);
            }
        }

        // store: lane holds pixel li, co = ch*16 + g*4 + r; pack qo pair -> float2
#pragma unroll
        for (int po = 0; po < 2; ++po) {
            const int oh = 2 * t + po;
#pragma unroll
            for (int r = 0; r < 4; ++r) {
                const int co = ch * 16 + g * 4 + r;
                float* yp = y + (((long)(n * COUT + co) * OH_ + oh) * OW_) + 2 * (us + li);
                *(float2*)yp = make_float2(acc[po][0][r], acc[po][1][r]);
            }
        }
    }
}

extern "C" void kernel_launch(void* const* d_in, const int* in_sizes, int n_in,
                              void* d_out, int out_size, void* d_ws, size_t ws_size,
                              hipStream_t stream) {
    const float* x = (const float*)d_in[0];
    const float* w = (const float*)d_in[1];
    const float* b = (const float*)d_in[2];
    float* y = (float*)d_out;

    unsigned short* wt = (unsigned short*)d_ws;                      // 32 KB
    unsigned short* xt = (unsigned short*)((char*)d_ws + 32768);     // padded bf16 x
    const size_t xt_bytes = (size_t)B_ * HP * WP * 32 * 2;           // ~17.3 MB

    hipMemsetAsync(xt, 0, xt_bytes, stream);                          // zero halo
    prep_w<<<1, 256, 0, stream>>>(w, wt);
    prep_x<<<dim3(H_ / 2, B_), 256, 0, stream>>>(x, xt);
    convt_mfma<<<dim3(W_ / 64, H_ / 2, B_), 256, 0, stream>>>(xt, wt, b, y);
}

// Round 4
// 172.718 us; speedup vs baseline: 1.7006x; 1.0480x over previous
//
#include <hip/hip_runtime.h>

#define B_    16
#define CIN   32
#define H_    128
#define W_    128
#define COUT  32
#define OH_   256
#define OW_   256

typedef __attribute__((ext_vector_type(8))) short bf8_t;   // 8 bf16 (4 VGPRs)
typedef __attribute__((ext_vector_type(4))) float f32x4;

__device__ inline unsigned int f2bf(float f) {
    unsigned int u = __float_as_uint(f);
    return (u + 0x7fffu + ((u >> 16) & 1u)) >> 16;   // RNE
}

// ---- weights f32 [ci][co][kh][kw] -> bf16 wt[khkw][co][ci] (32 KB, L2-hot) ----
__global__ __launch_bounds__(256)
void prep_w(const float* __restrict__ wgt, unsigned short* __restrict__ wt) {
    int e = blockIdx.x * 256 + threadIdx.x;          // 16384 total
    int khkw = e >> 10, co = (e >> 5) & 31, ci = e & 31;
    wt[e] = (unsigned short)f2bf(wgt[(ci * COUT + co) * 16 + khkw]);
}

// ---- fused: read f32 x, transpose+cvt into LDS, MFMA, store f32 y ----
// Block: 4 t-rows (8 output rows) x 64 u-cols, all 32 co. 512 thr = 8 waves.
// Wave role (compute): ch = wv&1 (co half), trow = wv>>1 (0..3).
// LDS cell (hr, wc) holds 32 ci as 4 chunks of 8; chunk g stored at slot
// g ^ ((iw>>1)&3) so the MFMA-frag ds_read_b128s are 2-way (free) only.
__global__ __launch_bounds__(512)
void convt_fused(const float* __restrict__ x,
                 const unsigned short* __restrict__ wt,
                 const float* __restrict__ bias,
                 float* __restrict__ y) {
    __shared__ unsigned short xs[6 * 66 * 32];   // 25344 B

    const int tid  = threadIdx.x;
    const int lane = tid & 63;
    const int wv   = tid >> 6;
    const int n    = blockIdx.z;
    const int t0   = blockIdx.y * 4;
    const int u0   = blockIdx.x * 64;

    // ---- stage: combos (hr 0..5, g' 0..3); wave wv does c = wv, wv+8, wv+16.
    // Per combo: lane -> wc = lane (iw = u0-1+lane), 8 ci-plane dword loads
    // (coalesced across lanes), pack 8 bf16, one ds_write_b128.
#pragma unroll
    for (int j = 0; j < 3; ++j) {
        const int c  = wv + j * 8;
        const int hr = c >> 2, gp = c & 3;
        const int ih = t0 - 1 + hr;
        const int iw = u0 - 1 + lane;
        const bool inb = ((unsigned)ih < H_) && ((unsigned)iw < W_);
        const float* xq = x + (((long)(n * CIN + gp * 8) * H_ + ih) * W_ + iw);
        float v[8];
#pragma unroll
        for (int k = 0; k < 8; ++k)
            v[k] = inb ? xq[(long)k * (H_ * W_)] : 0.0f;
        uint4 pk;
        pk.x = f2bf(v[0]) | (f2bf(v[1]) << 16);
        pk.y = f2bf(v[2]) | (f2bf(v[3]) << 16);
        pk.z = f2bf(v[4]) | (f2bf(v[5]) << 16);
        pk.w = f2bf(v[6]) | (f2bf(v[7]) << 16);
        const int slot = gp ^ ((iw >> 1) & 3);
        *(uint4*)(xs + (hr * 66 + lane) * 32 + slot * 8) = pk;
    }
    // tail cells wc = 64, 65 (24 combos x 2): threads 0..47, one cell each
    if (tid < 48) {
        const int c  = tid >> 1;
        const int hr = c >> 2, gp = c & 3;
        const int wc = 64 + (tid & 1);
        const int ih = t0 - 1 + hr;
        const int iw = u0 - 1 + wc;
        const bool inb = ((unsigned)ih < H_) && ((unsigned)iw < W_);
        const float* xq = x + (((long)(n * CIN + gp * 8) * H_ + ih) * W_ + iw);
        float v[8];
#pragma unroll
        for (int k = 0; k < 8; ++k)
            v[k] = inb ? xq[(long)k * (H_ * W_)] : 0.0f;
        uint4 pk;
        pk.x = f2bf(v[0]) | (f2bf(v[1]) << 16);
        pk.y = f2bf(v[2]) | (f2bf(v[3]) << 16);
        pk.z = f2bf(v[4]) | (f2bf(v[5]) << 16);
        pk.w = f2bf(v[6]) | (f2bf(v[7]) << 16);
        const int slot = gp ^ ((iw >> 1) & 3);
        *(uint4*)(xs + (hr * 66 + wc) * 32 + slot * 8) = pk;
    }

    const int ch   = wv & 1;      // co half
    const int trow = wv >> 1;     // 0..3
    const int g    = lane >> 4;   // k-chunk (ci group)
    const int li   = lane & 15;   // A: co row / B: pixel col

    // weight A-frags: 16 (kh,kw) for this wave's co-half (L2-hot)
    bf8_t wf[16];
    {
        const unsigned short* wp = wt + (ch * 16 + li) * 32 + g * 8;
#pragma unroll
        for (int kk = 0; kk < 16; ++kk)
            wf[kk] = *(const bf8_t*)(wp + kk * 1024);
    }
    float bias4[4];
#pragma unroll
    for (int r = 0; r < 4; ++r) bias4[r] = bias[ch * 16 + g * 4 + r];

    __syncthreads();

    const int t = t0 + trow;
#pragma unroll
    for (int st = 0; st < 4; ++st) {
        const int us = u0 + st * 16;

        // x B-frags xf[dh][dw], dh,dw in {0,1,2} ~ offsets -1,0,+1
        bf8_t xf[3][3];
#pragma unroll
        for (int dh = 0; dh < 3; ++dh) {
#pragma unroll
            for (int dw = 0; dw < 3; ++dw) {
                int wg   = us + li + dw - 1;
                int wl   = wg - (u0 - 1);
                int slot = g ^ ((wg >> 1) & 3);
                int hl   = trow + dh;
                xf[dh][dw] = *(const bf8_t*)(xs + (hl * 66 + wl) * 32 + slot * 8);
            }
        }

        f32x4 acc[2][2];
#pragma unroll
        for (int po = 0; po < 2; ++po)
#pragma unroll
            for (int qo = 0; qo < 2; ++qo)
                acc[po][qo] = (f32x4){bias4[0], bias4[1], bias4[2], bias4[3]};

#pragma unroll
        for (int po = 0; po < 2; ++po) {
            const int dh0 = po ? 2 : 1, kh0 = po ? 0 : 1;
            const int dh1 = po ? 1 : 0, kh1 = po ? 2 : 3;
#pragma unroll
            for (int qo = 0; qo < 2; ++qo) {
                const int dw0 = qo ? 2 : 1, kw0 = qo ? 0 : 1;
                const int dw1 = qo ? 1 : 0, kw1 = qo ? 2 : 3;
                acc[po][qo] = __builtin_amdgcn_mfma_f32_16x16x32_bf16(
                    wf[kh0 * 4 + kw0], xf[dh0][dw0], acc[po][qo], 0, 0, 0);
                acc[po][qo] = __builtin_amdgcn_mfma_f32_16x16x32_bf16(
                    wf[kh0 * 4 + kw1], xf[dh0][dw1], acc[po][qo], 0, 0, 0);
                acc[po][qo] = __builtin_amdgcn_mfma_f32_16x16x32_bf16(
                    wf[kh1 * 4 + kw0], xf[dh1][dw0], acc[po][qo], 0, 0, 0);
                acc[po][qo] = __builtin_amdgcn_mfma_f32_16x16x32_bf16(
                    wf[kh1 * 4 + kw1], xf[dh1][dw1], acc[po][qo], 0, 0, 0);
            }
        }

        // store: lane = pixel li; co = ch*16 + g*4 + r; (qo0,qo1) -> float2
#pragma unroll
        for (int po = 0; po < 2; ++po) {
            const int oh = 2 * t + po;
#pragma unroll
            for (int r = 0; r < 4; ++r) {
                const int co = ch * 16 + g * 4 + r;
                float* yp = y + (((long)(n * COUT + co) * OH_ + oh) * OW_) + 2 * (us + li);
                *(float2*)yp = make_float2(acc[po][0][r], acc[po][1][r]);
            }
        }
    }
}

extern "C" void kernel_launch(void* const* d_in, const int* in_sizes, int n_in,
                              void* d_out, int out_size, void* d_ws, size_t ws_size,
                              hipStream_t stream) {
    const float* x = (const float*)d_in[0];
    const float* w = (const float*)d_in[1];
    const float* b = (const float*)d_in[2];
    float* y = (float*)d_out;

    unsigned short* wt = (unsigned short*)d_ws;   // 32 KB

    prep_w<<<64, 256, 0, stream>>>(w, wt);
    convt_fused<<<dim3(W_ / 64, H_ / 4, B_), 512, 0, stream>>>(x, wt, b, y);
}

// Round 6
// 169.211 us; speedup vs baseline: 1.7358x; 1.0207x over previous
//
#include <hip/hip_runtime.h>

#define B_    16
#define CIN   32
#define H_    128
#define W_    128
#define COUT  32
#define OH_   256
#define OW_   256

typedef __attribute__((ext_vector_type(8))) short bf8_t;   // 8 bf16 (4 VGPRs)
typedef __attribute__((ext_vector_type(4))) float f32x4;

__device__ inline unsigned int f2bf(float f) {
    unsigned int u = __float_as_uint(f);
    return (u + 0x7fffu + ((u >> 16) & 1u)) >> 16;   // RNE
}

// ---- weights f32 [ci][co][kh][kw] -> bf16 wt[khkw][co][ci] (32 KB, L2-hot) ----
__global__ __launch_bounds__(256)
void prep_w(const float* __restrict__ wgt, unsigned short* __restrict__ wt) {
    int e = blockIdx.x * 256 + threadIdx.x;          // 16384 total
    int khkw = e >> 10, co = (e >> 5) & 31, ci = e & 31;
    wt[e] = (unsigned short)f2bf(wgt[(ci * COUT + co) * 16 + khkw]);
}

// ---- fused: read f32 x, transpose+cvt into LDS, MFMA, store f32 y ----
// Block: 4 t-rows (8 output rows) x 64 u-cols, all 32 co. 512 thr = 8 waves.
// Wave role (compute): ch = wv&1 (co half), trow = wv>>1 (0..3).
// po-split main loop keeps live regs ~110 so 2 blocks/CU stay resident.
__global__ __launch_bounds__(512, 4)
void convt_fused(const float* __restrict__ x,
                 const unsigned short* __restrict__ wt,
                 const float* __restrict__ bias,
                 float* __restrict__ y) {
    __shared__ unsigned short xs[6 * 66 * 32];   // 25344 B

    const int tid  = threadIdx.x;
    const int lane = tid & 63;
    const int wv   = tid >> 6;
    const int n    = blockIdx.z;
    const int t0   = blockIdx.y * 4;
    const int u0   = blockIdx.x * 64;

    // ---- stage: combos (hr 0..5, g' 0..3); wave wv does c = wv, wv+8, wv+16.
#pragma unroll
    for (int j = 0; j < 3; ++j) {
        const int c  = wv + j * 8;
        const int hr = c >> 2, gp = c & 3;
        const int ih = t0 - 1 + hr;
        const int iw = u0 - 1 + lane;
        const bool inb = ((unsigned)ih < H_) && ((unsigned)iw < W_);
        const float* xq = x + (((long)(n * CIN + gp * 8) * H_ + ih) * W_ + iw);
        float v[8];
#pragma unroll
        for (int k = 0; k < 8; ++k)
            v[k] = inb ? xq[(long)k * (H_ * W_)] : 0.0f;
        uint4 pk;
        pk.x = f2bf(v[0]) | (f2bf(v[1]) << 16);
        pk.y = f2bf(v[2]) | (f2bf(v[3]) << 16);
        pk.z = f2bf(v[4]) | (f2bf(v[5]) << 16);
        pk.w = f2bf(v[6]) | (f2bf(v[7]) << 16);
        const int slot = gp ^ ((iw >> 1) & 3);
        *(uint4*)(xs + (hr * 66 + lane) * 32 + slot * 8) = pk;
    }
    // tail cells wc = 64, 65 (24 combos x 2): threads 0..47, one cell each
    if (tid < 48) {
        const int c  = tid >> 1;
        const int hr = c >> 2, gp = c & 3;
        const int wc = 64 + (tid & 1);
        const int ih = t0 - 1 + hr;
        const int iw = u0 - 1 + wc;
        const bool inb = ((unsigned)ih < H_) && ((unsigned)iw < W_);
        const float* xq = x + (((long)(n * CIN + gp * 8) * H_ + ih) * W_ + iw);
        float v[8];
#pragma unroll
        for (int k = 0; k < 8; ++k)
            v[k] = inb ? xq[(long)k * (H_ * W_)] : 0.0f;
        uint4 pk;
        pk.x = f2bf(v[0]) | (f2bf(v[1]) << 16);
        pk.y = f2bf(v[2]) | (f2bf(v[3]) << 16);
        pk.z = f2bf(v[4]) | (f2bf(v[5]) << 16);
        pk.w = f2bf(v[6]) | (f2bf(v[7]) << 16);
        const int slot = gp ^ ((iw >> 1) & 3);
        *(uint4*)(xs + (hr * 66 + wc) * 32 + slot * 8) = pk;
    }

    const int ch   = wv & 1;      // co half
    const int trow = wv >> 1;     // 0..3
    const int g    = lane >> 4;   // k-chunk (ci group)
    const int li   = lane & 15;   // A: co row / B: pixel col

    float bias4[4];
#pragma unroll
    for (int r = 0; r < 4; ++r) bias4[r] = bias[ch * 16 + g * 4 + r];

    __syncthreads();

    const int t = t0 + trow;
    const unsigned short* wp = wt + (ch * 16 + li) * 32 + g * 8;

#pragma unroll
    for (int po = 0; po < 2; ++po) {
        const int kh0 = po ? 0 : 1, dh0 = po ? 2 : 1;   // tap row A
        const int kh1 = po ? 2 : 3, dh1 = po ? 1 : 0;   // tap row B

        // 8 weight A-frags for this po (L1/L2-hot)
        bf8_t wfA[4], wfB[4];
#pragma unroll
        for (int kw = 0; kw < 4; ++kw) {
            wfA[kw] = *(const bf8_t*)(wp + (kh0 * 4 + kw) * 1024);
            wfB[kw] = *(const bf8_t*)(wp + (kh1 * 4 + kw) * 1024);
        }

#pragma unroll
        for (int st = 0; st < 4; ++st) {
            const int us = u0 + st * 16;

            bf8_t xfA[3], xfB[3];
#pragma unroll
            for (int dw = 0; dw < 3; ++dw) {
                const int wg   = us + li + dw - 1;
                const int wl   = wg - (u0 - 1);
                const int slot = g ^ ((wg >> 1) & 3);
                xfA[dw] = *(const bf8_t*)(xs + ((trow + dh0) * 66 + wl) * 32 + slot * 8);
                xfB[dw] = *(const bf8_t*)(xs + ((trow + dh1) * 66 + wl) * 32 + slot * 8);
            }

            f32x4 acc[2];
#pragma unroll
            for (int qo = 0; qo < 2; ++qo)
                acc[qo] = (f32x4){bias4[0], bias4[1], bias4[2], bias4[3]};

#pragma unroll
            for (int qo = 0; qo < 2; ++qo) {
                const int dw0 = qo ? 2 : 1, kw0 = qo ? 0 : 1;
                const int dw1 = qo ? 1 : 0, kw1 = qo ? 2 : 3;
                acc[qo] = __builtin_amdgcn_mfma_f32_16x16x32_bf16(
                    wfA[kw0], xfA[dw0], acc[qo], 0, 0, 0);
                acc[qo] = __builtin_amdgcn_mfma_f32_16x16x32_bf16(
                    wfA[kw1], xfA[dw1], acc[qo], 0, 0, 0);
                acc[qo] = __builtin_amdgcn_mfma_f32_16x16x32_bf16(
                    wfB[kw0], xfB[dw0], acc[qo], 0, 0, 0);
                acc[qo] = __builtin_amdgcn_mfma_f32_16x16x32_bf16(
                    wfB[kw1], xfB[dw1], acc[qo], 0, 0, 0);
            }

            // store: lane = pixel li; co = ch*16 + g*4 + r; (qo0,qo1) -> float2
            const int oh = 2 * t + po;
#pragma unroll
            for (int r = 0; r < 4; ++r) {
                const int co = ch * 16 + g * 4 + r;
                float* yp = y + (((long)(n * COUT + co) * OH_ + oh) * OW_) + 2 * (us + li);
                *(float2*)yp = make_float2(acc[0][r], acc[1][r]);
            }
        }
    }
}

extern "C" void kernel_launch(void* const* d_in, const int* in_sizes, int n_in,
                              void* d_out, int out_size, void* d_ws, size_t ws_size,
                              hipStream_t stream) {
    const float* x = (const float*)d_in[0];
    const float* w = (const float*)d_in[1];
    const float* b = (const float*)d_in[2];
    float* y = (float*)d_out;

    unsigned short* wt = (unsigned short*)d_ws;   // 32 KB

    prep_w<<<64, 256, 0, stream>>>(w, wt);
    convt_fused<<<dim3(W_ / 64, H_ / 4, B_), 512, 0, stream>>>(x, wt, b, y);
}